// Round 11
// baseline (139.213 us; speedup 1.0000x reference)
//
#include <hip/hip_runtime.h>
#include <math.h>

#define N_ 16
#define H_ 512
#define W_ 512
#define HW_ (H_ * W_)
#define BAND 8              // output rows per block
#define GAMMA_ 2.0f

__device__ __forceinline__ float wave_reduce(float v) {
#pragma unroll
    for (int off = 32; off > 0; off >>= 1)
        v += __shfl_down(v, off, 64);
    return v;
}

// Pass A: sum(weight_raw). Only needs box(x0), box(x2), box(d^2), d = x0-x2,
// since box(d) = box(x0)-box(x2). Reads channels 0 and 2 only.
__global__ __launch_bounds__(256) void passA(const float* __restrict__ x,
                                             float* __restrict__ scalars) {
    __shared__ float rowbuf[3][W_];   // 6144 B
    __shared__ float red[4];

    const int tid = threadIdx.x;
    const int c0 = tid * 2;
    const int y0 = blockIdx.x * BAND;
    const int b = blockIdx.y;
    const float* xb = x + (size_t)b * (3 * HW_);
    const float inv81 = 1.0f / 81.0f;

    float va[3][2];
#pragma unroll
    for (int f = 0; f < 3; ++f) va[f][0] = va[f][1] = 0.0f;

    auto rowlite = [&](int r, float sgn) {
        int rr = r & (H_ - 1);
        const float* p = xb + rr * W_ + c0;
        float2 a0 = *(const float2*)(p);
        float2 a2 = *(const float2*)(p + 2 * HW_);
#pragma unroll
        for (int i = 0; i < 2; ++i) {
            float x0 = i ? a0.y : a0.x;
            float x2 = i ? a2.y : a2.x;
            float d = x0 - x2;
            va[0][i] = fmaf(sgn, x0, va[0][i]);
            va[1][i] = fmaf(sgn, x2, va[1][i]);
            va[2][i] = fmaf(sgn, d * d, va[2][i]);
        }
    };

#pragma unroll
    for (int k = 0; k < 9; ++k) rowlite(y0 - 4 + k, 1.0f);

    float accwr = 0.0f;
    for (int y = y0; y < y0 + BAND; ++y) {
#pragma unroll
        for (int f = 0; f < 3; ++f)
            *(float2*)&rowbuf[f][c0] = make_float2(va[f][0], va[f][1]);
        __syncthreads();

        float hs[3][2];
#pragma unroll
        for (int f = 0; f < 3; ++f) {
            float2 v[5];
#pragma unroll
            for (int j = 0; j < 5; ++j)
                v[j] = *(const float2*)&rowbuf[f][(c0 + 2 * j - 4) & (W_ - 1)];
            float s0 = ((v[0].x + v[0].y) + (v[1].x + v[1].y)) +
                       ((v[2].x + v[2].y) + (v[3].x + v[3].y)) + v[4].x;
            hs[f][0] = s0;
            hs[f][1] = s0 - v[0].x + v[4].y;
        }
#pragma unroll
        for (int i = 0; i < 2; ++i) {
            float md = (hs[0][i] - hs[1][i]) * inv81;
            accwr += (2.0f / 3.0f) * (hs[2][i] * inv81 - md * md);
        }
        __syncthreads();

        if (y + 1 < y0 + BAND) {
            rowlite(y + 5, 1.0f);
            rowlite(y - 4, -1.0f);
        }
    }

    float s = wave_reduce(accwr);
    if ((tid & 63) == 0) red[tid >> 6] = s;
    __syncthreads();
    if (tid == 0) atomicAdd(&scalars[0], (red[0] + red[1]) + (red[2] + red[3]));
}

// Pass B: recompute all 6 fields; w = exp(-coef*wr); reduce sum(w), sum(w*diff).
__global__ __launch_bounds__(256) void passB(const float* __restrict__ x,
                                             float* __restrict__ scalars) {
    __shared__ float rowbuf[6][W_];   // 12288 B
    __shared__ float red[8];

    const int tid = threadIdx.x;
    const int c0 = tid * 2;
    const int y0 = blockIdx.x * BAND;
    const int b = blockIdx.y;
    const float* xb = x + (size_t)b * (3 * HW_);
    const float inv81 = 1.0f / 81.0f;
    const float coef = GAMMA_ * (float)HW_ / scalars[0];

    float vs[6][2];
#pragma unroll
    for (int f = 0; f < 6; ++f) vs[f][0] = vs[f][1] = 0.0f;

    auto row_update = [&](int r, float sgn) {
        int rr = r & (H_ - 1);
        const float* p = xb + rr * W_ + c0;
        float2 a0 = *(const float2*)(p);
        float2 a1 = *(const float2*)(p + HW_);
        float2 a2 = *(const float2*)(p + 2 * HW_);
#pragma unroll
        for (int i = 0; i < 2; ++i) {
            float x0 = i ? a0.y : a0.x;
            float x1 = i ? a1.y : a1.x;
            float x2 = i ? a2.y : a2.x;
            float yv = (x0 + x1 + x2) * (1.0f / 3.0f);
            float d = x0 - x2;
            vs[0][i] = fmaf(sgn, x0, vs[0][i]);
            vs[1][i] = fmaf(sgn, x1, vs[1][i]);
            vs[2][i] = fmaf(sgn, x2, vs[2][i]);
            vs[3][i] = fmaf(sgn, x0 * x0 + x1 * x1 + x2 * x2, vs[3][i]);
            vs[4][i] = fmaf(sgn, yv * yv, vs[4][i]);
            vs[5][i] = fmaf(sgn, d * d, vs[5][i]);
        }
    };

#pragma unroll
    for (int k = 0; k < 9; ++k) row_update(y0 - 4 + k, 1.0f);

    float accw = 0.0f, accwd = 0.0f;

    for (int y = y0; y < y0 + BAND; ++y) {
#pragma unroll
        for (int f = 0; f < 6; ++f)
            *(float2*)&rowbuf[f][c0] = make_float2(vs[f][0], vs[f][1]);
        __syncthreads();

        float hs[6][2];
#pragma unroll
        for (int f = 0; f < 6; ++f) {
            float2 v[5];
#pragma unroll
            for (int j = 0; j < 5; ++j)
                v[j] = *(const float2*)&rowbuf[f][(c0 + 2 * j - 4) & (W_ - 1)];
            float s0 = ((v[0].x + v[0].y) + (v[1].x + v[1].y)) +
                       ((v[2].x + v[2].y) + (v[3].x + v[3].y)) + v[4].x;
            hs[f][0] = s0;
            hs[f][1] = s0 - v[0].x + v[4].y;
        }

#pragma unroll
        for (int i = 0; i < 2; ++i) {
            float B0 = hs[0][i] * inv81, B1 = hs[1][i] * inv81, B2 = hs[2][i] * inv81;
            float alpha = (hs[3][i] * inv81 - (B0 * B0 + B1 * B1 + B2 * B2)) * (1.0f / 3.0f);
            float my = (B0 + B1 + B2) * (1.0f / 3.0f);
            float beta = hs[4][i] * inv81 - my * my;
            float md = B0 - B2;
            float wr = (2.0f / 3.0f) * (hs[5][i] * inv81 - md * md);
            float df = alpha - beta;
            float w = __expf(-coef * wr);
            accw += w;
            accwd += w * df;
        }
        __syncthreads();

        if (y + 1 < y0 + BAND) {
            row_update(y + 5, 1.0f);
            row_update(y - 4, -1.0f);
        }
    }

    float s0 = wave_reduce(accw);
    float s1 = wave_reduce(accwd);
    if ((tid & 63) == 0) {
        red[tid >> 6] = s0;
        red[4 + (tid >> 6)] = s1;
    }
    __syncthreads();
    if (tid == 0) {
        atomicAdd(&scalars[1], (red[0] + red[1]) + (red[2] + red[3]));
        atomicAdd(&scalars[2], (red[4] + red[5]) + (red[6] + red[7]));
    }
}

__global__ void final_kernel(const float* __restrict__ scalars, float* __restrict__ out) {
    out[0] = 1.5f * scalars[2] / scalars[1];
}

extern "C" void kernel_launch(void* const* d_in, const int* in_sizes, int n_in,
                              void* d_out, int out_size, void* d_ws, size_t ws_size,
                              hipStream_t stream) {
    const float* x = (const float*)d_in[0];
    float* out = (float*)d_out;
    float* scalars = (float*)d_ws;  // [0]=sum(wr), [1]=sum(w), [2]=sum(w*diff)

    hipMemsetAsync(d_ws, 0, 16, stream);

    dim3 grid(H_ / BAND, N_);   // 64 x 16 = 1024 blocks
    passA<<<grid, 256, 0, stream>>>(x, scalars);
    passB<<<grid, 256, 0, stream>>>(x, scalars);
    final_kernel<<<1, 1, 0, stream>>>(scalars, out);
}